// Round 11
// baseline (242.407 us; speedup 1.0000x reference)
//
#include <hip/hip_runtime.h>
#include <cstring>

#define D 128
#define ROW 16512                 // D + D*D
#define DTF (1.0f/4095.0f)
#define HSTEP (64.0f/4095.0f)     // Zs scale: Zs = (64*dt)*B
#define H4F  (256.0f/4095.0f)     // coarse checkpoint step
#define LDA 132
#define LDB 132

#define XCP_OFF 4096              // x0 vector
#define MAT_OFF 12416

// slot map (each slot = 16384 floats = one 128x128 matrix)
#define S_ZT      3               // Zs transposed
#define S_V(m)    (4+(m))         // V_m = W0*Zs^m, m=0..6 (row-major)
#define S_AT(J)   (11+(J))        // W(256J)^T, J=0..15
#define S_BMT(J)  (27+(J))        // W(256J+128)^T, J=0..14
#define S_PT      42              // PhiT_J row-major, J=0..14

struct __align__(16) F4 { float v[4]; };
typedef float f4v __attribute__((ext_vector_type(4)));

__device__ __forceinline__ float* slotp(float* ws, int k){ return ws + MAT_OFF + (size_t)k*16384; }
__device__ __forceinline__ const float* slotpc(const float* ws, int k){ return ws + MAT_OFF + (size_t)k*16384; }

struct CFX { float cf[64][5]; float cx[64][7]; };  // M^i (deg4), M^(64j) (deg6), /64^m scaled
struct CMB { float c[31][7]; };                    // rows: A_J (J=0..15), BM_J (J=0..14)
struct EK  { double e[4][4]; };                    // [z^m](M-1)^k / 64^m, k=1..4, m=1..4

// ---------------- 256-thread strip-matmul pieces ----------------
__device__ __forceinline__ void ldA(const float* A, int r0, float (*As)[LDA]) {
  const F4* A4 = (const F4*)(A + (size_t)r0*128);
  for (int q = threadIdx.x; q < 512; q += 256) {
    F4 x = A4[q];
    *(F4*)&As[q>>5][(q&31)<<2] = x;
  }
}
__device__ __forceinline__ void mmcT(const float (*As)[LDA], const float (*Bs)[LDB], F4& o0, F4& o1) {
  const int rl = threadIdx.x >> 5, c0 = (threadIdx.x & 31) << 2;
  F4 a0s, a1s;
  #pragma unroll
  for (int e = 0; e < 4; ++e) { a0s.v[e] = 0.f; a1s.v[e] = 0.f; }
  #pragma unroll 8
  for (int k = 0; k < 128; ++k) {
    const F4 bv = *(const F4*)&Bs[k][c0];
    const float a0 = As[rl][k], a1 = As[rl+8][k];
    #pragma unroll
    for (int e = 0; e < 4; ++e) {
      a0s.v[e] = fmaf(a0, bv.v[e], a0s.v[e]);
      a1s.v[e] = fmaf(a1, bv.v[e], a1s.v[e]);
    }
  }
  o0 = a0s; o1 = a1s;
}

// ---------------- launch 1: V-chain + misc + Horner A^T/BM^T (unchanged) ----------------
__global__ __launch_bounds__(256) void k_vchain(const float* y0, const float* Bm,
                                                float* ws, float* out, CMB cmb) {
  __shared__ float As[16][LDA];
  __shared__ float Bs[128][LDB];
  int b = blockIdx.x, t = threadIdx.x;
  const float* W0 = y0 + D;
  const int rl = t >> 5, c0 = (t & 31) << 2;
  if (b < 48) {
    int m = (b >> 3) + 1, strip = b & 7;
    const F4* B4 = (const F4*)Bm;
    for (int q = t; q < 4096; q += 256) {
      F4 x = B4[q]; F4 o;
      #pragma unroll
      for (int e = 0; e < 4; ++e) o.v[e] = HSTEP * x.v[e];
      *(F4*)&Bs[q>>5][(q&31)<<2] = o;
    }
    ldA(W0, strip*16, As);
    __syncthreads();
    F4 o0, o1;
    for (int p = 0; p < m; ++p) {
      mmcT(As, Bs, o0, o1);
      if (p+1 < m) {
        __syncthreads();
        *(F4*)&As[rl][c0] = o0;
        *(F4*)&As[rl+8][c0] = o1;
        __syncthreads();
      }
    }
    float* Vp = slotp(ws, S_V(m));
    *(F4*)&Vp[(size_t)(strip*16+rl)*128 + c0]   = o0;
    *(F4*)&Vp[(size_t)(strip*16+rl+8)*128 + c0] = o1;
  } else if (b < 52) {
    int base = (b-48)*1024;
    for (int i = 0; i < 4; ++i) {
      int q = base + t + i*256;
      ((F4*)out)[q] = ((const F4*)y0)[q];
    }
  } else if (b == 52) {
    if (t < 128) { out[16384+t] = y0[16384+t]; ws[XCP_OFF+t] = y0[t]; }
  } else if (b < 57) {
    int base = (b-53)*1024;
    F4* Vp = (F4*)slotp(ws, S_V(0));
    for (int i = 0; i < 4; ++i) { int q = base + t + i*256; Vp[q] = ((const F4*)W0)[q]; }
  } else if (b < 61) {
    int base = (b-57)*1024;
    float* ZT = slotp(ws, S_ZT);
    for (int i = 0; i < 4; ++i) {
      int q = base + t + i*256;
      F4 x = ((const F4*)Bm)[q];
      int r = q>>5, cc2 = (q&31)<<2;
      #pragma unroll
      for (int e = 0; e < 4; ++e) ZT[(size_t)(cc2+e)*128 + r] = HSTEP * x.v[e];
    }
  } else {
    int idx = b - 61;
    int mat = idx >> 3, strip = idx & 7;
    int slot = (mat < 16) ? S_AT(mat) : S_BMT(mat-16);
    const float* cc = cmb.c[mat];
    const F4* B4 = (const F4*)Bm;
    for (int q = t; q < 4096; q += 256) {
      F4 x = B4[q]; F4 o;
      #pragma unroll
      for (int e = 0; e < 4; ++e) o.v[e] = HSTEP * x.v[e];
      *(F4*)&Bs[q>>5][(q&31)<<2] = o;
    }
    const F4 s0 = *(const F4*)&W0[(size_t)(strip*16+rl)*128 + c0];
    const F4 s1 = *(const F4*)&W0[(size_t)(strip*16+rl+8)*128 + c0];
    F4 t0, t1;
    #pragma unroll
    for (int e = 0; e < 4; ++e) { t0.v[e] = cc[6]*s0.v[e]; t1.v[e] = cc[6]*s1.v[e]; }
    *(F4*)&As[rl][c0] = t0; *(F4*)&As[rl+8][c0] = t1;
    __syncthreads();
    F4 o0, o1;
    for (int k = 5; k >= 0; --k) {
      mmcT(As, Bs, o0, o1);
      #pragma unroll
      for (int e = 0; e < 4; ++e) { o0.v[e] += cc[k]*s0.v[e]; o1.v[e] += cc[k]*s1.v[e]; }
      if (k > 0) {
        __syncthreads();
        *(F4*)&As[rl][c0] = o0; *(F4*)&As[rl+8][c0] = o1;
        __syncthreads();
      }
    }
    // write transposed: AT[c][r] = A[r][c]
    float* Cp = slotp(ws, slot);
    int r0 = strip*16 + rl;
    #pragma unroll
    for (int e = 0; e < 4; ++e) {
      Cp[(size_t)(c0+e)*128 + r0]     = o0.v[e];
      Cp[(size_t)(c0+e)*128 + r0 + 8] = o1.v[e];
    }
  }
}

// ---------------- launch 2: PhiT_J one-shot (transposed RK4 polynomial) ----------------
// PhiT = I + (h/6)[a + 4b + ap + h(ab + b^2 + b*ap) + (h^2/2)(ab^2 + b^2*ap) + (h^3/4) ab^2*ap]
// with a = AT_J, b = BMT_J, ap = AT_{J+1}; emitted row-major (chain-ready).
__global__ __launch_bounds__(256) void k_phiT(float* ws) {
  __shared__ float Bs1[128][LDB];   // b full
  __shared__ float Bs2[128][LDB];   // ap full
  __shared__ float Aw[16][LDA];     // sa -> u1 -> u2 -> v1
  __shared__ float Asb[16][LDA];    // sb
  int J = blockIdx.x >> 3, strip = blockIdx.x & 7, t = threadIdx.x;
  const int rl = t >> 5, c0 = (t & 31) << 2;
  const float* a  = slotpc(ws, S_AT(J));
  const float* b  = slotpc(ws, S_BMT(J));
  const float* ap = slotpc(ws, S_AT(J+1));
  { const F4* s=(const F4*)b;  for (int q=t;q<4096;q+=256) *(F4*)&Bs1[q>>5][(q&31)<<2]=s[q]; }
  { const F4* s=(const F4*)ap; for (int q=t;q<4096;q+=256) *(F4*)&Bs2[q>>5][(q&31)<<2]=s[q]; }
  ldA(a, strip*16, Aw);
  ldA(b, strip*16, Asb);
  __syncthreads();
  F4 pa0, pa1;
  {
    const F4 p0 = *(const F4*)&ap[(size_t)(strip*16+rl)*128 + c0];
    const F4 p1 = *(const F4*)&ap[(size_t)(strip*16+rl+8)*128 + c0];
    #pragma unroll
    for (int e = 0; e < 4; ++e) {
      pa0.v[e] = Aw[rl][c0+e]   + 4.f*Asb[rl][c0+e]   + p0.v[e];
      pa1.v[e] = Aw[rl+8][c0+e] + 4.f*Asb[rl+8][c0+e] + p1.v[e];
    }
  }
  const float h = H4F, wh = h, wh2 = 0.5f*h*h, wh3 = 0.25f*h*h*h;
  F4 o0, o1;
  // u1 = sa*b
  mmcT(Aw, Bs1, o0, o1);
  #pragma unroll
  for (int e = 0; e < 4; ++e) { pa0.v[e] += wh*o0.v[e]; pa1.v[e] += wh*o1.v[e]; }
  __syncthreads();
  *(F4*)&Aw[rl][c0] = o0; *(F4*)&Aw[rl+8][c0] = o1;
  __syncthreads();
  // u2 = u1*b
  mmcT(Aw, Bs1, o0, o1);
  #pragma unroll
  for (int e = 0; e < 4; ++e) { pa0.v[e] += wh2*o0.v[e]; pa1.v[e] += wh2*o1.v[e]; }
  __syncthreads();
  *(F4*)&Aw[rl][c0] = o0; *(F4*)&Aw[rl+8][c0] = o1;
  __syncthreads();
  // u3 = u2*ap
  mmcT(Aw, Bs2, o0, o1);
  #pragma unroll
  for (int e = 0; e < 4; ++e) { pa0.v[e] += wh3*o0.v[e]; pa1.v[e] += wh3*o1.v[e]; }
  __syncthreads();
  // v1 = sb*b
  mmcT(Asb, Bs1, o0, o1);
  #pragma unroll
  for (int e = 0; e < 4; ++e) { pa0.v[e] += wh*o0.v[e]; pa1.v[e] += wh*o1.v[e]; }
  *(F4*)&Aw[rl][c0] = o0; *(F4*)&Aw[rl+8][c0] = o1;   // safe: u3 reads synced above
  __syncthreads();
  // v2 = sb*ap
  mmcT(Asb, Bs2, o0, o1);
  #pragma unroll
  for (int e = 0; e < 4; ++e) { pa0.v[e] += wh*o0.v[e]; pa1.v[e] += wh*o1.v[e]; }
  // v3 = v1*ap
  mmcT(Aw, Bs2, o0, o1);
  #pragma unroll
  for (int e = 0; e < 4; ++e) { pa0.v[e] += wh2*o0.v[e]; pa1.v[e] += wh2*o1.v[e]; }
  // write PhiT row-major with identity
  float* PT = slotp(ws, S_PT + J);
  const float h6 = h / 6.0f;
  #pragma unroll
  for (int half = 0; half < 2; ++half) {
    int r = strip*16 + rl + half*8;
    F4 pa = half ? pa1 : pa0;
    F4 o;
    #pragma unroll
    for (int e = 0; e < 4; ++e)
      o.v[e] = ((r == c0+e) ? 1.0f : 0.0f) + h6*pa.v[e];
    *(F4*)&PT[(size_t)r*128 + c0] = o;
  }
}

// ---------------- launch 3: fused x-path (PhiT chain + P/Q) + dense W fill ----------------
__global__ __launch_bounds__(256, 4) void k_fused(float* ws, float* out, EK ek, CFX cfx) {
  __shared__ __align__(16) float smf[3520];   // 14080 B (x-path)
  __shared__ float coef[4][8];                // fill coefs
  int t = threadIdx.x;

  if (blockIdx.x >= 64) {
    // ---- dense W fill: block bb writes output rows n = 4bb..4bb+3 contiguously ----
    int bb = blockIdx.x - 64;
    if (t < 32) {
      int d = t >> 3, p = t & 7;
      if (p < 7) {
        int n = 4*bb + d, j = n >> 6, i = n & 63;
        float s = 0.f;
        #pragma unroll
        for (int m = 0; m <= 4; ++m) {
          int qm = p - m;
          if (qm >= 0) s = fmaf(cfx.cf[i][m], cfx.cx[j][qm], s);
        }
        coef[d][p] = s;
      }
    }
    __syncthreads();
    const F4* Vp[7];
    #pragma unroll
    for (int m = 0; m < 7; ++m) Vp[m] = (const F4*)slotpc(ws, S_V(m));
    size_t base = (size_t)(4*bb)*ROW + D;
    for (int k = 0; k < 16; ++k) {
      int q = t + 256*k;
      F4 v[7];
      #pragma unroll
      for (int m = 0; m < 7; ++m) v[m] = Vp[m][q];
      #pragma unroll
      for (int d = 0; d < 4; ++d) {
        f4v o = {0.f, 0.f, 0.f, 0.f};
        #pragma unroll
        for (int p = 0; p < 7; ++p) {
          float c = coef[d][p];
          #pragma unroll
          for (int e = 0; e < 4; ++e) o[e] = fmaf(c, v[p].v[e], o[e]);
        }
        __builtin_nontemporal_store(o, (f4v*)(out + base + (size_t)d*ROW + 4*(size_t)q));
      }
    }
    return;
  }

  // ---- x path: PhiT chain + P/Q-factorized Heun jumps ----
  float* za   = smf;            // [5][128]
  float* zb   = smf + 640;      // [5][128]
  float* Pv   = smf + 1280;     // [5][128]
  float* Qv   = smf + 1920;     // [5][128]
  float* xv   = smf + 2560;
  float* kv   = smf + 2688;
  float* red  = smf + 2816;
  float* uv   = smf + 2944;
  float (*cfs)[5] = (float (*)[5])(smf + 3200);  // [64][5]

  int J = blockIdx.x >> 2, w = blockIdx.x & 3;
  int r = t & 127, hh = t >> 7;
  if (t < 128) xv[t] = ws[XCP_OFF + t];
  if (t < 64) { // cfs[il][m] = [Zs^m] M^(w*64+il), closed form via binomials
    double di = (double)(w*64 + t);
    double b1 = di, b2 = b1*(di-1.0)*0.5, b3 = b2*(di-2.0)*(1.0/3.0), b4 = b3*(di-3.0)*0.25;
    cfs[t][0] = 1.f;
    cfs[t][1] = (float)(b1*ek.e[0][0]);
    cfs[t][2] = (float)(b1*ek.e[0][1] + b2*ek.e[1][1]);
    cfs[t][3] = (float)(b1*ek.e[0][2] + b2*ek.e[1][2] + b3*ek.e[2][2]);
    cfs[t][4] = (float)(b1*ek.e[0][3] + b2*ek.e[1][3] + b3*ek.e[2][3] + b4*ek.e[3][3]);
  }
  __syncthreads();

  // serial checkpoint chain via PhiT matrices: xv = x_{256J} (<= 15 matvecs)
  for (int jj = 0; jj < J; ++jj) {
    const float* PT = slotpc(ws, S_PT + jj);
    float s = 0.f;
    #pragma unroll 8
    for (int c = hh*64; c < hh*64+64; ++c) s = fmaf(PT[(size_t)c*128 + r], xv[c], s);
    if (hh) red[r] = s;
    __syncthreads();
    if (!hh) xv[r] = s + red[r];
    __syncthreads();
  }
  if (J > 0 && w == 0 && t < 128) out[(size_t)(256*J)*ROW + t] = xv[t];

  const float* ATJ = slotpc(ws, S_AT(J));
  { // kv = A_J * xv
    float s = 0.f;
    #pragma unroll 8
    for (int c = hh*64; c < hh*64 + 64; ++c) s = fmaf(ATJ[(size_t)c*128 + r], xv[c], s);
    if (hh) red[r] = s;
    __syncthreads();
    if (!hh) kv[r] = s + red[r];
    __syncthreads();
  }
  if (t < 128) { za[t] = xv[t]; zb[t] = kv[t]; }
  __syncthreads();
  const float* ZTg = slotpc(ws, S_ZT);
  for (int m = 1; m <= 4; ++m) {
    float sa = 0.f, sb = 0.f;
    #pragma unroll 8
    for (int c = hh*64; c < hh*64 + 64; ++c) {
      float zv = ZTg[(size_t)c*128 + r];
      sa = fmaf(zv, za[(m-1)*128 + c], sa);
      sb = fmaf(zv, zb[(m-1)*128 + c], sb);
    }
    if (hh) { red[r] = sa; uv[r] = sb; }
    __syncthreads();
    if (!hh) { za[m*128 + r] = sa + red[r]; zb[m*128 + r] = sb + uv[r]; }
    __syncthreads();
  }
  // P[m] = A_J za[m], Q[m] = A_J zb[m]
  for (int m = 0; m <= 4; ++m) {
    float sa = 0.f, sb = 0.f;
    #pragma unroll 8
    for (int c = hh*64; c < hh*64 + 64; ++c) {
      float av = ATJ[(size_t)c*128 + r];
      sa = fmaf(av, za[m*128 + c], sa);
      sb = fmaf(av, zb[m*128 + c], sb);
    }
    if (hh) { red[r] = sa; uv[r] = sb; }
    __syncthreads();
    if (!hh) { Pv[m*128 + r] = sa + red[r]; Qv[m*128 + r] = sb + uv[r]; }
    __syncthreads();
  }
  // out rows: x_{256J+i} = xv + 0.5 h_i (kv + sum_m cfs[i][m](P_m + h_i Q_m))
  float xr = xv[r], kr = kv[r];
  #pragma unroll 4
  for (int l = 0; l < 32; ++l) {
    int il = 2*l + hh;
    int i = w*64 + il;
    if (i >= 1) {
      float hi = i * DTF;
      float k2r = 0.f;
      #pragma unroll
      for (int m = 0; m <= 4; ++m)
        k2r = fmaf(cfs[il][m], Pv[m*128 + r] + hi*Qv[m*128 + r], k2r);
      out[(size_t)(256*J + i)*ROW + r] = xr + 0.5f*hi*(kr + k2r);
    }
  }
}

// ---------------- host ----------------
static void pmul16(const double* a, const double* b, double* o) {
  double r[16];
  for (int i = 0; i < 16; ++i) r[i] = 0.0;
  for (int i = 0; i < 16; ++i) {
    double ai = a[i];
    if (ai == 0.0) continue;
    for (int k = 0; i + k < 16; ++k) r[i+k] += ai*b[k];
  }
  for (int i = 0; i < 16; ++i) o[i] = r[i];
}

extern "C" void kernel_launch(void* const* d_in, const int* in_sizes, int n_in,
                              void* d_out, int out_size, void* d_ws, size_t ws_size,
                              hipStream_t stream) {
  (void)in_sizes; (void)n_in; (void)out_size; (void)ws_size;
  const float* y0 = (const float*)d_in[1];
  const float* Bm = (const float*)d_in[2];
  float* out = (float*)d_out;
  float* ws  = (float*)d_ws;

  // Tsit5 stability polynomial M(z), z = dt*B, via C_s recurrence
  double At[7][7]; memset(At, 0, sizeof(At));
  At[2][1] = 0.161;
  At[3][1] = -0.008480655492356989; At[3][2] = 0.335480655492357;
  At[4][1] = 2.8971530571054935;  At[4][2] = -6.359448489975075;  At[4][3] = 4.3622954328695815;
  At[5][1] = 5.325864828439257;   At[5][2] = -11.748883564062828; At[5][3] = 7.4955393428898365;  At[5][4] = -0.09249506636175525;
  At[6][1] = 5.86145544294642;    At[6][2] = -12.92096931784711;  At[6][3] = 8.159367898576159;   At[6][4] = -0.071584973281401; At[6][5] = -0.028269050394068383;
  const double dB[7] = {0, 0.09646076681806523, 0.01, 0.4798896504144996,
                        1.379008574103742, -3.290069515436081, 2.324710524099774};
  double C[7][16]; memset(C, 0, sizeof(C));
  C[1][0] = 1.0;
  for (int s = 2; s <= 6; ++s) {
    C[s][0] = 1.0;
    for (int k = 1; k < 16; ++k) {
      double acc = 0.0;
      for (int l = 1; l < s; ++l) acc += At[s][l]*C[l][k-1];
      C[s][k] = acc;
    }
  }
  double M[16]; memset(M, 0, sizeof(M)); M[0] = 1.0;
  for (int k = 1; k < 16; ++k) {
    double acc = 0.0;
    for (int s = 1; s <= 6; ++s) acc += dB[s]*C[s][k-1];
    M[k] = acc;
  }
  double p64m[16]; p64m[0] = 1.0;
  for (int m = 1; m < 16; ++m) p64m[m] = p64m[m-1]*64.0;

  // harvest scaled coefficient rows of M^n along one pmul chain
  CFX cfx; memset(&cfx, 0, sizeof(cfx));
  CMB cmb; memset(&cmb, 0, sizeof(cmb));
  double cur[16]; memset(cur, 0, sizeof(cur)); cur[0] = 1.0;
  for (int n = 0; n <= 4032; ++n) {
    if (n < 64)  for (int m = 0; m <= 4; ++m) cfx.cf[n][m] = (float)(cur[m]/p64m[m]);
    if ((n & 63) == 0) {
      int j = n >> 6;
      if (j < 64) for (int m = 0; m <= 6; ++m) cfx.cx[j][m] = (float)(cur[m]/p64m[m]);
    }
    if ((n & 255) == 0) {
      int J = n >> 8;
      if (J <= 15) for (int m = 0; m <= 6; ++m) cmb.c[J][m] = (float)(cur[m]/p64m[m]);
    }
    if ((n & 255) == 128) {
      int J = (n - 128) >> 8;
      if (J <= 14) for (int m = 0; m <= 6; ++m) cmb.c[16+J][m] = (float)(cur[m]/p64m[m]);
    }
    pmul16(cur, M, cur);
  }

  // EK: [z^m](M-1)^k / 64^m for the closed-form M^i coefficients
  EK ek; memset(&ek, 0, sizeof(ek));
  {
    double e1[5] = {0,0,0,0,0}, e2[5] = {0,0,0,0,0}, e3[5] = {0,0,0,0,0}, e4[5] = {0,0,0,0,0};
    for (int m = 1; m <= 4; ++m) e1[m] = M[m];
    for (int m = 2; m <= 4; ++m) for (int a = 1; a < m; ++a) e2[m] += e1[a]*e1[m-a];
    for (int m = 3; m <= 4; ++m) for (int a = 2; a < m; ++a) e3[m] += e2[a]*e1[m-a];
    e4[4] = e3[3]*e1[1];
    for (int m = 1; m <= 4; ++m) {
      ek.e[0][m-1] = e1[m]/p64m[m];
      ek.e[1][m-1] = e2[m]/p64m[m];
      ek.e[2][m-1] = e3[m]/p64m[m];
      ek.e[3][m-1] = e4[m]/p64m[m];
    }
  }

  k_vchain<<<309, 256, 0, stream>>>(y0, Bm, ws, out, cmb);
  k_phiT<<<120, 256, 0, stream>>>(ws);
  k_fused<<<1088, 256, 0, stream>>>(ws, out, ek, cfx);
}

// Round 12
// 150.736 us; speedup vs baseline: 1.6082x; 1.6082x over previous
//
#include <hip/hip_runtime.h>
#include <cstring>

#define D 128
#define ROW 16512                 // D + D*D
#define DTF (1.0f/4095.0f)
#define HSTEP (64.0f/4095.0f)     // Zs scale: Zs = (64*dt)*B
#define H4F  (256.0f/4095.0f)     // coarse checkpoint step
#define LDA 132
#define LDB 132

#define XCP_OFF 4096              // x0 vector
#define MAT_OFF 12416

// slot map (each slot = 16384 floats = one 128x128 matrix)
#define S_ZT      3               // Zs transposed
#define S_V(m)    (4+(m))         // V_m = W0*Zs^m, m=0..6 (row-major)
#define S_AT(J)   (11+(J))        // W(256J)^T, J=0..15
#define S_BMT(J)  (27+(J))        // W(256J+128)^T, J=0..14
#define S_PT      42              // PhiT_J row-major, J=0..14

struct __align__(16) F4 { float v[4]; };
typedef float f4v __attribute__((ext_vector_type(4)));

__device__ __forceinline__ float* slotp(float* ws, int k){ return ws + MAT_OFF + (size_t)k*16384; }
__device__ __forceinline__ const float* slotpc(const float* ws, int k){ return ws + MAT_OFF + (size_t)k*16384; }

struct CFX { float cf[64][5]; float cx[64][7]; };  // M^i (deg4), M^(64j) (deg6), /64^m scaled
struct CMB { float c[31][7]; };                    // rows: A_J (J=0..15), BM_J (J=0..14)
struct EK  { double e[4][4]; };                    // [z^m](M-1)^k / 64^m, k=1..4, m=1..4

// ---------------- 256-thread strip-matmul pieces ----------------
__device__ __forceinline__ void ldA(const float* A, int r0, float (*As)[LDA]) {
  const F4* A4 = (const F4*)(A + (size_t)r0*128);
  for (int q = threadIdx.x; q < 512; q += 256) {
    F4 x = A4[q];
    *(F4*)&As[q>>5][(q&31)<<2] = x;
  }
}
__device__ __forceinline__ void mmcT(const float (*As)[LDA], const float (*Bs)[LDB], F4& o0, F4& o1) {
  const int rl = threadIdx.x >> 5, c0 = (threadIdx.x & 31) << 2;
  F4 a0s, a1s;
  #pragma unroll
  for (int e = 0; e < 4; ++e) { a0s.v[e] = 0.f; a1s.v[e] = 0.f; }
  #pragma unroll 8
  for (int k = 0; k < 128; ++k) {
    const F4 bv = *(const F4*)&Bs[k][c0];
    const float a0 = As[rl][k], a1 = As[rl+8][k];
    #pragma unroll
    for (int e = 0; e < 4; ++e) {
      a0s.v[e] = fmaf(a0, bv.v[e], a0s.v[e]);
      a1s.v[e] = fmaf(a1, bv.v[e], a1s.v[e]);
    }
  }
  o0 = a0s; o1 = a1s;
}

// ---------------- launch 1: V-chain + misc + Horner A^T/BM^T ----------------
__global__ __launch_bounds__(256) void k_vchain(const float* y0, const float* Bm,
                                                float* ws, float* out, CMB cmb) {
  __shared__ float As[16][LDA];
  __shared__ float Bs[128][LDB];
  int b = blockIdx.x, t = threadIdx.x;
  const float* W0 = y0 + D;
  const int rl = t >> 5, c0 = (t & 31) << 2;
  if (b < 48) {
    int m = (b >> 3) + 1, strip = b & 7;
    const F4* B4 = (const F4*)Bm;
    for (int q = t; q < 4096; q += 256) {
      F4 x = B4[q]; F4 o;
      #pragma unroll
      for (int e = 0; e < 4; ++e) o.v[e] = HSTEP * x.v[e];
      *(F4*)&Bs[q>>5][(q&31)<<2] = o;
    }
    ldA(W0, strip*16, As);
    __syncthreads();
    F4 o0, o1;
    for (int p = 0; p < m; ++p) {
      mmcT(As, Bs, o0, o1);
      if (p+1 < m) {
        __syncthreads();
        *(F4*)&As[rl][c0] = o0;
        *(F4*)&As[rl+8][c0] = o1;
        __syncthreads();
      }
    }
    float* Vp = slotp(ws, S_V(m));
    *(F4*)&Vp[(size_t)(strip*16+rl)*128 + c0]   = o0;
    *(F4*)&Vp[(size_t)(strip*16+rl+8)*128 + c0] = o1;
  } else if (b < 52) {
    int base = (b-48)*1024;
    for (int i = 0; i < 4; ++i) {
      int q = base + t + i*256;
      ((F4*)out)[q] = ((const F4*)y0)[q];
    }
  } else if (b == 52) {
    if (t < 128) { out[16384+t] = y0[16384+t]; ws[XCP_OFF+t] = y0[t]; }
  } else if (b < 57) {
    int base = (b-53)*1024;
    F4* Vp = (F4*)slotp(ws, S_V(0));
    for (int i = 0; i < 4; ++i) { int q = base + t + i*256; Vp[q] = ((const F4*)W0)[q]; }
  } else if (b < 61) {
    int base = (b-57)*1024;
    float* ZT = slotp(ws, S_ZT);
    for (int i = 0; i < 4; ++i) {
      int q = base + t + i*256;
      F4 x = ((const F4*)Bm)[q];
      int r = q>>5, cc2 = (q&31)<<2;
      #pragma unroll
      for (int e = 0; e < 4; ++e) ZT[(size_t)(cc2+e)*128 + r] = HSTEP * x.v[e];
    }
  } else {
    int idx = b - 61;
    int mat = idx >> 3, strip = idx & 7;
    int slot = (mat < 16) ? S_AT(mat) : S_BMT(mat-16);
    const float* cc = cmb.c[mat];
    const F4* B4 = (const F4*)Bm;
    for (int q = t; q < 4096; q += 256) {
      F4 x = B4[q]; F4 o;
      #pragma unroll
      for (int e = 0; e < 4; ++e) o.v[e] = HSTEP * x.v[e];
      *(F4*)&Bs[q>>5][(q&31)<<2] = o;
    }
    const F4 s0 = *(const F4*)&W0[(size_t)(strip*16+rl)*128 + c0];
    const F4 s1 = *(const F4*)&W0[(size_t)(strip*16+rl+8)*128 + c0];
    F4 t0, t1;
    #pragma unroll
    for (int e = 0; e < 4; ++e) { t0.v[e] = cc[6]*s0.v[e]; t1.v[e] = cc[6]*s1.v[e]; }
    *(F4*)&As[rl][c0] = t0; *(F4*)&As[rl+8][c0] = t1;
    __syncthreads();
    F4 o0, o1;
    for (int k = 5; k >= 0; --k) {
      mmcT(As, Bs, o0, o1);
      #pragma unroll
      for (int e = 0; e < 4; ++e) { o0.v[e] += cc[k]*s0.v[e]; o1.v[e] += cc[k]*s1.v[e]; }
      if (k > 0) {
        __syncthreads();
        *(F4*)&As[rl][c0] = o0; *(F4*)&As[rl+8][c0] = o1;
        __syncthreads();
      }
    }
    // write transposed: AT[c][r] = A[r][c]
    float* Cp = slotp(ws, slot);
    int r0 = strip*16 + rl;
    #pragma unroll
    for (int e = 0; e < 4; ++e) {
      Cp[(size_t)(c0+e)*128 + r0]     = o0.v[e];
      Cp[(size_t)(c0+e)*128 + r0 + 8] = o1.v[e];
    }
  }
}

// ---------------- launch 2: PhiT_J one-shot (transposed RK4 polynomial) ----------------
__global__ __launch_bounds__(256) void k_phiT(float* ws) {
  __shared__ float Bs1[128][LDB];   // b full
  __shared__ float Bs2[128][LDB];   // ap full
  __shared__ float Aw[16][LDA];     // sa -> u1 -> u2 -> v1
  __shared__ float Asb[16][LDA];    // sb
  int J = blockIdx.x >> 3, strip = blockIdx.x & 7, t = threadIdx.x;
  const int rl = t >> 5, c0 = (t & 31) << 2;
  const float* a  = slotpc(ws, S_AT(J));
  const float* b  = slotpc(ws, S_BMT(J));
  const float* ap = slotpc(ws, S_AT(J+1));
  { const F4* s=(const F4*)b;  for (int q=t;q<4096;q+=256) *(F4*)&Bs1[q>>5][(q&31)<<2]=s[q]; }
  { const F4* s=(const F4*)ap; for (int q=t;q<4096;q+=256) *(F4*)&Bs2[q>>5][(q&31)<<2]=s[q]; }
  ldA(a, strip*16, Aw);
  ldA(b, strip*16, Asb);
  __syncthreads();
  F4 pa0, pa1;
  {
    const F4 p0 = *(const F4*)&ap[(size_t)(strip*16+rl)*128 + c0];
    const F4 p1 = *(const F4*)&ap[(size_t)(strip*16+rl+8)*128 + c0];
    #pragma unroll
    for (int e = 0; e < 4; ++e) {
      pa0.v[e] = Aw[rl][c0+e]   + 4.f*Asb[rl][c0+e]   + p0.v[e];
      pa1.v[e] = Aw[rl+8][c0+e] + 4.f*Asb[rl+8][c0+e] + p1.v[e];
    }
  }
  const float h = H4F, wh = h, wh2 = 0.5f*h*h, wh3 = 0.25f*h*h*h;
  F4 o0, o1;
  // u1 = sa*b
  mmcT(Aw, Bs1, o0, o1);
  #pragma unroll
  for (int e = 0; e < 4; ++e) { pa0.v[e] += wh*o0.v[e]; pa1.v[e] += wh*o1.v[e]; }
  __syncthreads();
  *(F4*)&Aw[rl][c0] = o0; *(F4*)&Aw[rl+8][c0] = o1;
  __syncthreads();
  // u2 = u1*b
  mmcT(Aw, Bs1, o0, o1);
  #pragma unroll
  for (int e = 0; e < 4; ++e) { pa0.v[e] += wh2*o0.v[e]; pa1.v[e] += wh2*o1.v[e]; }
  __syncthreads();
  *(F4*)&Aw[rl][c0] = o0; *(F4*)&Aw[rl+8][c0] = o1;
  __syncthreads();
  // u3 = u2*ap
  mmcT(Aw, Bs2, o0, o1);
  #pragma unroll
  for (int e = 0; e < 4; ++e) { pa0.v[e] += wh3*o0.v[e]; pa1.v[e] += wh3*o1.v[e]; }
  __syncthreads();
  // v1 = sb*b
  mmcT(Asb, Bs1, o0, o1);
  #pragma unroll
  for (int e = 0; e < 4; ++e) { pa0.v[e] += wh*o0.v[e]; pa1.v[e] += wh*o1.v[e]; }
  *(F4*)&Aw[rl][c0] = o0; *(F4*)&Aw[rl+8][c0] = o1;
  __syncthreads();
  // v2 = sb*ap
  mmcT(Asb, Bs2, o0, o1);
  #pragma unroll
  for (int e = 0; e < 4; ++e) { pa0.v[e] += wh*o0.v[e]; pa1.v[e] += wh*o1.v[e]; }
  // v3 = v1*ap
  mmcT(Aw, Bs2, o0, o1);
  #pragma unroll
  for (int e = 0; e < 4; ++e) { pa0.v[e] += wh2*o0.v[e]; pa1.v[e] += wh2*o1.v[e]; }
  float* PT = slotp(ws, S_PT + J);
  const float h6 = h / 6.0f;
  #pragma unroll
  for (int half = 0; half < 2; ++half) {
    int r = strip*16 + rl + half*8;
    F4 pa = half ? pa1 : pa0;
    F4 o;
    #pragma unroll
    for (int e = 0; e < 4; ++e)
      o.v[e] = ((r == c0+e) ? 1.0f : 0.0f) + h6*pa.v[e];
    *(F4*)&PT[(size_t)r*128 + c0] = o;
  }
}

// ---------------- launch 3: fused x-path (PhiT chain + P/Q) + column-slice W fill ----------------
__global__ __launch_bounds__(256, 4) void k_fused(float* ws, float* out, EK ek, CFX cfx) {
  __shared__ __align__(16) float smf[3520];   // 14080 B
  int t = threadIdx.x;

  if (blockIdx.x >= 64) {
    // ---- W fill (column-slice, 28 KB V-footprint per block) ----
    float (*coefL)[7] = (float (*)[7])smf;
    int bb = blockIdx.x - 64;
    int j = bb >> 4, strip = bb & 15;
    for (int idx = t; idx < 448; idx += 256) {
      int i = idx / 7, p = idx - i*7;
      float s = 0.f;
      #pragma unroll
      for (int m = 0; m <= 4; ++m) {
        int qm = p - m;
        if (qm >= 0) s = fmaf(cfx.cf[i][m], cfx.cx[j][qm], s);
      }
      coefL[i][p] = s;
    }
    int r = strip*8 + (t >> 5);
    int q = r*32 + (t & 31);
    F4 v[7];
    #pragma unroll
    for (int m = 0; m < 7; ++m) v[m] = ((const F4*)slotpc(ws, S_V(m)))[q];
    __syncthreads();
    #pragma unroll 4
    for (int i = 0; i < 64; ++i) {
      f4v o = {0.f, 0.f, 0.f, 0.f};
      #pragma unroll
      for (int p = 0; p < 7; ++p) {
        float c = coefL[i][p];
        #pragma unroll
        for (int e = 0; e < 4; ++e) o[e] = fmaf(c, v[p].v[e], o[e]);
      }
      __builtin_nontemporal_store(o, (f4v*)(out + (size_t)(j*64 + i)*ROW + D + 4*(size_t)q));
    }
    return;
  }

  // ---- x path: PhiT chain + P/Q-factorized Heun jumps ----
  float* za   = smf;            // [5][128]
  float* zb   = smf + 640;      // [5][128]
  float* Pv   = smf + 1280;     // [5][128]
  float* Qv   = smf + 1920;     // [5][128]
  float* xv   = smf + 2560;
  float* kv   = smf + 2688;
  float* red  = smf + 2816;
  float* uv   = smf + 2944;
  float (*cfs)[5] = (float (*)[5])(smf + 3200);  // [64][5]

  int J = blockIdx.x >> 2, w = blockIdx.x & 3;
  int r = t & 127, hh = t >> 7;
  if (t < 128) xv[t] = ws[XCP_OFF + t];
  if (t < 64) { // cfs[il][m] = [Zs^m] M^(w*64+il), closed form via binomials
    double di = (double)(w*64 + t);
    double b1 = di, b2 = b1*(di-1.0)*0.5, b3 = b2*(di-2.0)*(1.0/3.0), b4 = b3*(di-3.0)*0.25;
    cfs[t][0] = 1.f;
    cfs[t][1] = (float)(b1*ek.e[0][0]);
    cfs[t][2] = (float)(b1*ek.e[0][1] + b2*ek.e[1][1]);
    cfs[t][3] = (float)(b1*ek.e[0][2] + b2*ek.e[1][2] + b3*ek.e[2][2]);
    cfs[t][4] = (float)(b1*ek.e[0][3] + b2*ek.e[1][3] + b3*ek.e[2][3] + b4*ek.e[3][3]);
  }
  __syncthreads();

  // serial checkpoint chain via PhiT matrices: xv = x_{256J} (<= 15 matvecs)
  for (int jj = 0; jj < J; ++jj) {
    const float* PT = slotpc(ws, S_PT + jj);
    float s = 0.f;
    #pragma unroll 8
    for (int c = hh*64; c < hh*64+64; ++c) s = fmaf(PT[(size_t)c*128 + r], xv[c], s);
    if (hh) red[r] = s;
    __syncthreads();
    if (!hh) xv[r] = s + red[r];
    __syncthreads();
  }
  if (J > 0 && w == 0 && t < 128) out[(size_t)(256*J)*ROW + t] = xv[t];

  const float* ATJ = slotpc(ws, S_AT(J));
  { // kv = A_J * xv
    float s = 0.f;
    #pragma unroll 8
    for (int c = hh*64; c < hh*64 + 64; ++c) s = fmaf(ATJ[(size_t)c*128 + r], xv[c], s);
    if (hh) red[r] = s;
    __syncthreads();
    if (!hh) kv[r] = s + red[r];
    __syncthreads();
  }
  if (t < 128) { za[t] = xv[t]; zb[t] = kv[t]; }
  __syncthreads();
  const float* ZTg = slotpc(ws, S_ZT);
  for (int m = 1; m <= 4; ++m) {
    float sa = 0.f, sb = 0.f;
    #pragma unroll 8
    for (int c = hh*64; c < hh*64 + 64; ++c) {
      float zv = ZTg[(size_t)c*128 + r];
      sa = fmaf(zv, za[(m-1)*128 + c], sa);
      sb = fmaf(zv, zb[(m-1)*128 + c], sb);
    }
    if (hh) { red[r] = sa; uv[r] = sb; }
    __syncthreads();
    if (!hh) { za[m*128 + r] = sa + red[r]; zb[m*128 + r] = sb + uv[r]; }
    __syncthreads();
  }
  // P[m] = A_J za[m], Q[m] = A_J zb[m]
  for (int m = 0; m <= 4; ++m) {
    float sa = 0.f, sb = 0.f;
    #pragma unroll 8
    for (int c = hh*64; c < hh*64 + 64; ++c) {
      float av = ATJ[(size_t)c*128 + r];
      sa = fmaf(av, za[m*128 + c], sa);
      sb = fmaf(av, zb[m*128 + c], sb);
    }
    if (hh) { red[r] = sa; uv[r] = sb; }
    __syncthreads();
    if (!hh) { Pv[m*128 + r] = sa + red[r]; Qv[m*128 + r] = sb + uv[r]; }
    __syncthreads();
  }
  // out rows: x_{256J+i} = xv + 0.5 h_i (kv + sum_m cfs[i][m](P_m + h_i Q_m))
  float xr = xv[r], kr = kv[r];
  #pragma unroll 4
  for (int l = 0; l < 32; ++l) {
    int il = 2*l + hh;
    int i = w*64 + il;
    if (i >= 1) {
      float hi = i * DTF;
      float k2r = 0.f;
      #pragma unroll
      for (int m = 0; m <= 4; ++m)
        k2r = fmaf(cfs[il][m], Pv[m*128 + r] + hi*Qv[m*128 + r], k2r);
      out[(size_t)(256*J + i)*ROW + r] = xr + 0.5f*hi*(kr + k2r);
    }
  }
}

// ---------------- host ----------------
static void pmul16(const double* a, const double* b, double* o) {
  double r[16];
  for (int i = 0; i < 16; ++i) r[i] = 0.0;
  for (int i = 0; i < 16; ++i) {
    double ai = a[i];
    if (ai == 0.0) continue;
    for (int k = 0; i + k < 16; ++k) r[i+k] += ai*b[k];
  }
  for (int i = 0; i < 16; ++i) o[i] = r[i];
}

extern "C" void kernel_launch(void* const* d_in, const int* in_sizes, int n_in,
                              void* d_out, int out_size, void* d_ws, size_t ws_size,
                              hipStream_t stream) {
  (void)in_sizes; (void)n_in; (void)out_size; (void)ws_size;
  const float* y0 = (const float*)d_in[1];
  const float* Bm = (const float*)d_in[2];
  float* out = (float*)d_out;
  float* ws  = (float*)d_ws;

  // Tsit5 stability polynomial M(z), z = dt*B, via C_s recurrence
  double At[7][7]; memset(At, 0, sizeof(At));
  At[2][1] = 0.161;
  At[3][1] = -0.008480655492356989; At[3][2] = 0.335480655492357;
  At[4][1] = 2.8971530571054935;  At[4][2] = -6.359448489975075;  At[4][3] = 4.3622954328695815;
  At[5][1] = 5.325864828439257;   At[5][2] = -11.748883564062828; At[5][3] = 7.4955393428898365;  At[5][4] = -0.09249506636175525;
  At[6][1] = 5.86145544294642;    At[6][2] = -12.92096931784711;  At[6][3] = 8.159367898576159;   At[6][4] = -0.071584973281401; At[6][5] = -0.028269050394068383;
  const double dB[7] = {0, 0.09646076681806523, 0.01, 0.4798896504144996,
                        1.379008574103742, -3.290069515436081, 2.324710524099774};
  double C[7][16]; memset(C, 0, sizeof(C));
  C[1][0] = 1.0;
  for (int s = 2; s <= 6; ++s) {
    C[s][0] = 1.0;
    for (int k = 1; k < 16; ++k) {
      double acc = 0.0;
      for (int l = 1; l < s; ++l) acc += At[s][l]*C[l][k-1];
      C[s][k] = acc;
    }
  }
  double M[16]; memset(M, 0, sizeof(M)); M[0] = 1.0;
  for (int k = 1; k < 16; ++k) {
    double acc = 0.0;
    for (int s = 1; s <= 6; ++s) acc += dB[s]*C[s][k-1];
    M[k] = acc;
  }
  double p64m[16]; p64m[0] = 1.0;
  for (int m = 1; m < 16; ++m) p64m[m] = p64m[m-1]*64.0;

  // harvest scaled coefficient rows of M^n along one pmul chain
  CFX cfx; memset(&cfx, 0, sizeof(cfx));
  CMB cmb; memset(&cmb, 0, sizeof(cmb));
  double cur[16]; memset(cur, 0, sizeof(cur)); cur[0] = 1.0;
  for (int n = 0; n <= 4032; ++n) {
    if (n < 64)  for (int m = 0; m <= 4; ++m) cfx.cf[n][m] = (float)(cur[m]/p64m[m]);
    if ((n & 63) == 0) {
      int j = n >> 6;
      if (j < 64) for (int m = 0; m <= 6; ++m) cfx.cx[j][m] = (float)(cur[m]/p64m[m]);
    }
    if ((n & 255) == 0) {
      int J = n >> 8;
      if (J <= 15) for (int m = 0; m <= 6; ++m) cmb.c[J][m] = (float)(cur[m]/p64m[m]);
    }
    if ((n & 255) == 128) {
      int J = (n - 128) >> 8;
      if (J <= 14) for (int m = 0; m <= 6; ++m) cmb.c[16+J][m] = (float)(cur[m]/p64m[m]);
    }
    pmul16(cur, M, cur);
  }

  // EK: [z^m](M-1)^k / 64^m for the closed-form M^i coefficients
  EK ek; memset(&ek, 0, sizeof(ek));
  {
    double e1[5] = {0,0,0,0,0}, e2[5] = {0,0,0,0,0}, e3[5] = {0,0,0,0,0}, e4[5] = {0,0,0,0,0};
    for (int m = 1; m <= 4; ++m) e1[m] = M[m];
    for (int m = 2; m <= 4; ++m) for (int a = 1; a < m; ++a) e2[m] += e1[a]*e1[m-a];
    for (int m = 3; m <= 4; ++m) for (int a = 2; a < m; ++a) e3[m] += e2[a]*e1[m-a];
    e4[4] = e3[3]*e1[1];
    for (int m = 1; m <= 4; ++m) {
      ek.e[0][m-1] = e1[m]/p64m[m];
      ek.e[1][m-1] = e2[m]/p64m[m];
      ek.e[2][m-1] = e3[m]/p64m[m];
      ek.e[3][m-1] = e4[m]/p64m[m];
    }
  }

  k_vchain<<<309, 256, 0, stream>>>(y0, Bm, ws, out, cmb);
  k_phiT<<<120, 256, 0, stream>>>(ws);
  k_fused<<<1088, 256, 0, stream>>>(ws, out, ek, cfx);
}

// Round 14
// 141.307 us; speedup vs baseline: 1.7155x; 1.0667x over previous
//
#include <hip/hip_runtime.h>
#include <cstring>

#define D 128
#define ROW 16512                 // D + D*D
#define DTF (1.0f/4095.0f)
#define HSTEP (64.0f/4095.0f)     // Zs scale: Zs = (64*dt)*B
#define H4F  (256.0f/4095.0f)     // coarse checkpoint step
#define LDA 132
#define LDB 132
#define NV  5                     // V basis degree-4 (err ~1.5e-4 rel << bf16 floor)

#define XCP_OFF 4096              // x0 vector
#define MAT_OFF 12416

// slot map (each slot = 16384 floats = one 128x128 matrix)
#define S_ZT      3               // Zs transposed
#define S_V(m)    (4+(m))         // V_m = W0*Zs^m, m=0..4 (row-major)
#define S_AT(J)   (11+(J))        // W(256J)^T, J=0..15
#define S_BMT(J)  (27+(J))        // W(256J+128)^T, J=0..14
#define S_PT      42              // PhiT_J row-major, J=0..14

struct __align__(16) F4 { float v[4]; };
typedef float f4v __attribute__((ext_vector_type(4)));

__device__ __forceinline__ float* slotp(float* ws, int k){ return ws + MAT_OFF + (size_t)k*16384; }
__device__ __forceinline__ const float* slotpc(const float* ws, int k){ return ws + MAT_OFF + (size_t)k*16384; }

struct CFX { float cf[64][5]; float cx[64][5]; };  // M^i (deg4), M^(64j) (deg4), /64^m scaled
struct CMB { float c[31][7]; };                    // rows: A_J (J=0..15), BM_J (J=0..14), deg-6
struct EK  { double e[4][4]; };                    // [z^m](M-1)^k / 64^m, k=1..4, m=1..4

// ---------------- 256-thread strip-matmul pieces ----------------
__device__ __forceinline__ void ldA(const float* A, int r0, float (*As)[LDA]) {
  const F4* A4 = (const F4*)(A + (size_t)r0*128);
  for (int q = threadIdx.x; q < 512; q += 256) {
    F4 x = A4[q];
    *(F4*)&As[q>>5][(q&31)<<2] = x;
  }
}
__device__ __forceinline__ void mmcT(const float (*As)[LDA], const float (*Bs)[LDB], F4& o0, F4& o1) {
  const int rl = threadIdx.x >> 5, c0 = (threadIdx.x & 31) << 2;
  F4 a0s, a1s;
  #pragma unroll
  for (int e = 0; e < 4; ++e) { a0s.v[e] = 0.f; a1s.v[e] = 0.f; }
  #pragma unroll 8
  for (int k = 0; k < 128; ++k) {
    const F4 bv = *(const F4*)&Bs[k][c0];
    const float a0 = As[rl][k], a1 = As[rl+8][k];
    #pragma unroll
    for (int e = 0; e < 4; ++e) {
      a0s.v[e] = fmaf(a0, bv.v[e], a0s.v[e]);
      a1s.v[e] = fmaf(a1, bv.v[e], a1s.v[e]);
    }
  }
  o0 = a0s; o1 = a1s;
}

// ---------------- launch 1: V-chain + misc + Horner A^T/BM^T ----------------
__global__ __launch_bounds__(256) void k_vchain(const float* y0, const float* Bm,
                                                float* ws, float* out, CMB cmb) {
  __shared__ float As[16][LDA];
  __shared__ float Bs[128][LDB];
  int b = blockIdx.x, t = threadIdx.x;
  const float* W0 = y0 + D;
  const int rl = t >> 5, c0 = (t & 31) << 2;
  if (b < 32) {
    int m = (b >> 3) + 1, strip = b & 7;
    const F4* B4 = (const F4*)Bm;
    for (int q = t; q < 4096; q += 256) {
      F4 x = B4[q]; F4 o;
      #pragma unroll
      for (int e = 0; e < 4; ++e) o.v[e] = HSTEP * x.v[e];
      *(F4*)&Bs[q>>5][(q&31)<<2] = o;
    }
    ldA(W0, strip*16, As);
    __syncthreads();
    F4 o0, o1;
    for (int p = 0; p < m; ++p) {
      mmcT(As, Bs, o0, o1);
      if (p+1 < m) {
        __syncthreads();
        *(F4*)&As[rl][c0] = o0;
        *(F4*)&As[rl+8][c0] = o1;
        __syncthreads();
      }
    }
    float* Vp = slotp(ws, S_V(m));
    *(F4*)&Vp[(size_t)(strip*16+rl)*128 + c0]   = o0;
    *(F4*)&Vp[(size_t)(strip*16+rl+8)*128 + c0] = o1;
  } else if (b < 36) {
    int base = (b-32)*1024;
    for (int i = 0; i < 4; ++i) {
      int q = base + t + i*256;
      ((F4*)out)[q] = ((const F4*)y0)[q];
    }
  } else if (b == 36) {
    if (t < 128) { out[16384+t] = y0[16384+t]; ws[XCP_OFF+t] = y0[t]; }
  } else if (b < 41) {
    int base = (b-37)*1024;
    F4* Vp = (F4*)slotp(ws, S_V(0));
    for (int i = 0; i < 4; ++i) { int q = base + t + i*256; Vp[q] = ((const F4*)W0)[q]; }
  } else if (b < 45) {
    int base = (b-41)*1024;
    float* ZT = slotp(ws, S_ZT);
    for (int i = 0; i < 4; ++i) {
      int q = base + t + i*256;
      F4 x = ((const F4*)Bm)[q];
      int r = q>>5, cc2 = (q&31)<<2;
      #pragma unroll
      for (int e = 0; e < 4; ++e) ZT[(size_t)(cc2+e)*128 + r] = HSTEP * x.v[e];
    }
  } else {
    int idx = b - 45;
    int mat = idx >> 3, strip = idx & 7;
    int slot = (mat < 16) ? S_AT(mat) : S_BMT(mat-16);
    const float* cc = cmb.c[mat];
    const F4* B4 = (const F4*)Bm;
    for (int q = t; q < 4096; q += 256) {
      F4 x = B4[q]; F4 o;
      #pragma unroll
      for (int e = 0; e < 4; ++e) o.v[e] = HSTEP * x.v[e];
      *(F4*)&Bs[q>>5][(q&31)<<2] = o;
    }
    const F4 s0 = *(const F4*)&W0[(size_t)(strip*16+rl)*128 + c0];
    const F4 s1 = *(const F4*)&W0[(size_t)(strip*16+rl+8)*128 + c0];
    F4 t0, t1;
    #pragma unroll
    for (int e = 0; e < 4; ++e) { t0.v[e] = cc[6]*s0.v[e]; t1.v[e] = cc[6]*s1.v[e]; }
    *(F4*)&As[rl][c0] = t0; *(F4*)&As[rl+8][c0] = t1;
    __syncthreads();
    F4 o0, o1;
    for (int k = 5; k >= 0; --k) {
      mmcT(As, Bs, o0, o1);
      #pragma unroll
      for (int e = 0; e < 4; ++e) { o0.v[e] += cc[k]*s0.v[e]; o1.v[e] += cc[k]*s1.v[e]; }
      if (k > 0) {
        __syncthreads();
        *(F4*)&As[rl][c0] = o0; *(F4*)&As[rl+8][c0] = o1;
        __syncthreads();
      }
    }
    // write transposed: AT[c][r] = A[r][c]
    float* Cp = slotp(ws, slot);
    int r0 = strip*16 + rl;
    #pragma unroll
    for (int e = 0; e < 4; ++e) {
      Cp[(size_t)(c0+e)*128 + r0]     = o0.v[e];
      Cp[(size_t)(c0+e)*128 + r0 + 8] = o1.v[e];
    }
  }
}

// ---------------- launch 2: PhiT_J one-shot (transposed RK4 polynomial) ----------------
__global__ __launch_bounds__(256) void k_phiT(float* ws) {
  __shared__ float Bs1[128][LDB];   // b full
  __shared__ float Bs2[128][LDB];   // ap full
  __shared__ float Aw[16][LDA];     // sa -> u1 -> u2 -> v1
  __shared__ float Asb[16][LDA];    // sb
  int J = blockIdx.x >> 3, strip = blockIdx.x & 7, t = threadIdx.x;
  const int rl = t >> 5, c0 = (t & 31) << 2;
  const float* a  = slotpc(ws, S_AT(J));
  const float* b  = slotpc(ws, S_BMT(J));
  const float* ap = slotpc(ws, S_AT(J+1));
  { const F4* s=(const F4*)b;  for (int q=t;q<4096;q+=256) *(F4*)&Bs1[q>>5][(q&31)<<2]=s[q]; }
  { const F4* s=(const F4*)ap; for (int q=t;q<4096;q+=256) *(F4*)&Bs2[q>>5][(q&31)<<2]=s[q]; }
  ldA(a, strip*16, Aw);
  ldA(b, strip*16, Asb);
  __syncthreads();
  F4 pa0, pa1;
  {
    const F4 p0 = *(const F4*)&ap[(size_t)(strip*16+rl)*128 + c0];
    const F4 p1 = *(const F4*)&ap[(size_t)(strip*16+rl+8)*128 + c0];
    #pragma unroll
    for (int e = 0; e < 4; ++e) {
      pa0.v[e] = Aw[rl][c0+e]   + 4.f*Asb[rl][c0+e]   + p0.v[e];
      pa1.v[e] = Aw[rl+8][c0+e] + 4.f*Asb[rl+8][c0+e] + p1.v[e];
    }
  }
  const float h = H4F, wh = h, wh2 = 0.5f*h*h, wh3 = 0.25f*h*h*h;
  F4 o0, o1;
  // u1 = sa*b
  mmcT(Aw, Bs1, o0, o1);
  #pragma unroll
  for (int e = 0; e < 4; ++e) { pa0.v[e] += wh*o0.v[e]; pa1.v[e] += wh*o1.v[e]; }
  __syncthreads();
  *(F4*)&Aw[rl][c0] = o0; *(F4*)&Aw[rl+8][c0] = o1;
  __syncthreads();
  // u2 = u1*b
  mmcT(Aw, Bs1, o0, o1);
  #pragma unroll
  for (int e = 0; e < 4; ++e) { pa0.v[e] += wh2*o0.v[e]; pa1.v[e] += wh2*o1.v[e]; }
  __syncthreads();
  *(F4*)&Aw[rl][c0] = o0; *(F4*)&Aw[rl+8][c0] = o1;
  __syncthreads();
  // u3 = u2*ap
  mmcT(Aw, Bs2, o0, o1);
  #pragma unroll
  for (int e = 0; e < 4; ++e) { pa0.v[e] += wh3*o0.v[e]; pa1.v[e] += wh3*o1.v[e]; }
  __syncthreads();
  // v1 = sb*b
  mmcT(Asb, Bs1, o0, o1);
  #pragma unroll
  for (int e = 0; e < 4; ++e) { pa0.v[e] += wh*o0.v[e]; pa1.v[e] += wh*o1.v[e]; }
  *(F4*)&Aw[rl][c0] = o0; *(F4*)&Aw[rl+8][c0] = o1;
  __syncthreads();
  // v2 = sb*ap
  mmcT(Asb, Bs2, o0, o1);
  #pragma unroll
  for (int e = 0; e < 4; ++e) { pa0.v[e] += wh*o0.v[e]; pa1.v[e] += wh*o1.v[e]; }
  // v3 = v1*ap
  mmcT(Aw, Bs2, o0, o1);
  #pragma unroll
  for (int e = 0; e < 4; ++e) { pa0.v[e] += wh2*o0.v[e]; pa1.v[e] += wh2*o1.v[e]; }
  float* PT = slotp(ws, S_PT + J);
  const float h6 = h / 6.0f;
  #pragma unroll
  for (int half = 0; half < 2; ++half) {
    int r = strip*16 + rl + half*8;
    F4 pa = half ? pa1 : pa0;
    F4 o;
    #pragma unroll
    for (int e = 0; e < 4; ++e)
      o.v[e] = ((r == c0+e) ? 1.0f : 0.0f) + h6*pa.v[e];
    *(F4*)&PT[(size_t)r*128 + c0] = o;
  }
}

// ---------------- launch 3: fused x-path + LDS-staged contiguous W fill ----------------
// blocks 0..63: (J,w) x-path; blocks 64..1087: fill (g = n-group of 16, qt = quarter)
__global__ __launch_bounds__(256, 2) void k_fused(float* ws, float* out, EK ek, CFX cfx) {
  __shared__ __align__(16) float smf[NV*4096];   // 80 KB
  int t = threadIdx.x;

  if (blockIdx.x >= 64) {
    // ---- W fill: stage V quarters to LDS, write 16 rows x 16 KB contiguous ----
    int bb = blockIdx.x - 64;
    int g = bb >> 2, qt = bb & 3;
    for (int m = 0; m < NV; ++m) {
      const F4* Vq = (const F4*)(slotpc(ws, S_V(m)) + qt*4096);
      F4* L = (F4*)&smf[m*4096];
      for (int q4 = t; q4 < 1024; q4 += 256) L[q4] = Vq[q4];
    }
    __syncthreads();
    for (int nn = 0; nn < 16; ++nn) {
      int n = g*16 + nn, j = n >> 6, i = n & 63;
      float c[5];
      #pragma unroll
      for (int p = 0; p < 5; ++p) {
        float s = 0.f;
        #pragma unroll
        for (int m = 0; m <= 4; ++m) {
          int qm = p - m;
          if (qm >= 0) s = fmaf(cfx.cf[i][m], cfx.cx[j][qm], s);
        }
        c[p] = s;
      }
      float* dst = out + (size_t)n*ROW + D + qt*4096;
      #pragma unroll
      for (int k = 0; k < 4; ++k) {           // quarter = 1024 F4 = 4 x 256 threads
        int qq = k*256 + t;                    // F4 index within quarter [0,1024)
        f4v o = {0.f, 0.f, 0.f, 0.f};
        #pragma unroll
        for (int m = 0; m < NV; ++m) {
          F4 v = *(const F4*)&smf[m*4096 + 4*qq];
          #pragma unroll
          for (int e = 0; e < 4; ++e) o[e] = fmaf(c[m], v.v[e], o[e]);
        }
        __builtin_nontemporal_store(o, (f4v*)(dst + 4*(size_t)qq));
      }
    }
    return;
  }

  // ---- x path: PhiT chain + P/Q-factorized Heun jumps (uses first 3520 floats of smf) ----
  float* za   = smf;            // [5][128]
  float* zb   = smf + 640;      // [5][128]
  float* Pv   = smf + 1280;     // [5][128]
  float* Qv   = smf + 1920;     // [5][128]
  float* xv   = smf + 2560;
  float* kv   = smf + 2688;
  float* red  = smf + 2816;
  float* uv   = smf + 2944;
  float (*cfs)[5] = (float (*)[5])(smf + 3200);  // [64][5]

  int J = blockIdx.x >> 2, w = blockIdx.x & 3;
  int r = t & 127, hh = t >> 7;
  if (t < 128) xv[t] = ws[XCP_OFF + t];
  if (t < 64) { // cfs[il][m] = [Zs^m] M^(w*64+il), closed form via binomials
    double di = (double)(w*64 + t);
    double b1 = di, b2 = b1*(di-1.0)*0.5, b3 = b2*(di-2.0)*(1.0/3.0), b4 = b3*(di-3.0)*0.25;
    cfs[t][0] = 1.f;
    cfs[t][1] = (float)(b1*ek.e[0][0]);
    cfs[t][2] = (float)(b1*ek.e[0][1] + b2*ek.e[1][1]);
    cfs[t][3] = (float)(b1*ek.e[0][2] + b2*ek.e[1][2] + b3*ek.e[2][2]);
    cfs[t][4] = (float)(b1*ek.e[0][3] + b2*ek.e[1][3] + b3*ek.e[2][3] + b4*ek.e[3][3]);
  }
  __syncthreads();

  // serial checkpoint chain via PhiT matrices: xv = x_{256J} (<= 15 matvecs)
  for (int jj = 0; jj < J; ++jj) {
    const float* PT = slotpc(ws, S_PT + jj);
    float s = 0.f;
    #pragma unroll 8
    for (int c = hh*64; c < hh*64+64; ++c) s = fmaf(PT[(size_t)c*128 + r], xv[c], s);
    if (hh) red[r] = s;
    __syncthreads();
    if (!hh) xv[r] = s + red[r];
    __syncthreads();
  }
  if (J > 0 && w == 0 && t < 128) out[(size_t)(256*J)*ROW + t] = xv[t];

  const float* ATJ = slotpc(ws, S_AT(J));
  { // kv = A_J * xv
    float s = 0.f;
    #pragma unroll 8
    for (int c = hh*64; c < hh*64 + 64; ++c) s = fmaf(ATJ[(size_t)c*128 + r], xv[c], s);
    if (hh) red[r] = s;
    __syncthreads();
    if (!hh) kv[r] = s + red[r];
    __syncthreads();
  }
  if (t < 128) { za[t] = xv[t]; zb[t] = kv[t]; }
  __syncthreads();
  const float* ZTg = slotpc(ws, S_ZT);
  for (int m = 1; m <= 4; ++m) {
    float sa = 0.f, sb = 0.f;
    #pragma unroll 8
    for (int c = hh*64; c < hh*64 + 64; ++c) {
      float zv = ZTg[(size_t)c*128 + r];
      sa = fmaf(zv, za[(m-1)*128 + c], sa);
      sb = fmaf(zv, zb[(m-1)*128 + c], sb);
    }
    if (hh) { red[r] = sa; uv[r] = sb; }
    __syncthreads();
    if (!hh) { za[m*128 + r] = sa + red[r]; zb[m*128 + r] = sb + uv[r]; }
    __syncthreads();
  }
  // P[m] = A_J za[m], Q[m] = A_J zb[m]
  for (int m = 0; m <= 4; ++m) {
    float sa = 0.f, sb = 0.f;
    #pragma unroll 8
    for (int c = hh*64; c < hh*64 + 64; ++c) {
      float av = ATJ[(size_t)c*128 + r];
      sa = fmaf(av, za[m*128 + c], sa);
      sb = fmaf(av, zb[m*128 + c], sb);
    }
    if (hh) { red[r] = sa; uv[r] = sb; }
    __syncthreads();
    if (!hh) { Pv[m*128 + r] = sa + red[r]; Qv[m*128 + r] = sb + uv[r]; }
    __syncthreads();
  }
  // out rows: x_{256J+i} = xv + 0.5 h_i (kv + sum_m cfs[i][m](P_m + h_i Q_m))
  float xr = xv[r], kr = kv[r];
  #pragma unroll 4
  for (int l = 0; l < 32; ++l) {
    int il = 2*l + hh;
    int i = w*64 + il;
    if (i >= 1) {
      float hi = i * DTF;
      float k2r = 0.f;
      #pragma unroll
      for (int m = 0; m <= 4; ++m)
        k2r = fmaf(cfs[il][m], Pv[m*128 + r] + hi*Qv[m*128 + r], k2r);
      out[(size_t)(256*J + i)*ROW + r] = xr + 0.5f*hi*(kr + k2r);
    }
  }
}

// ---------------- host ----------------
static void pmul16(const double* a, const double* b, double* o) {
  double r[16];
  for (int i = 0; i < 16; ++i) r[i] = 0.0;
  for (int i = 0; i < 16; ++i) {
    double ai = a[i];
    if (ai == 0.0) continue;
    for (int k = 0; i + k < 16; ++k) r[i+k] += ai*b[k];
  }
  for (int i = 0; i < 16; ++i) o[i] = r[i];
}

extern "C" void kernel_launch(void* const* d_in, const int* in_sizes, int n_in,
                              void* d_out, int out_size, void* d_ws, size_t ws_size,
                              hipStream_t stream) {
  (void)in_sizes; (void)n_in; (void)out_size; (void)ws_size;
  const float* y0 = (const float*)d_in[1];
  const float* Bm = (const float*)d_in[2];
  float* out = (float*)d_out;
  float* ws  = (float*)d_ws;

  // Tsit5 stability polynomial M(z), z = dt*B, via C_s recurrence
  double At[7][7]; memset(At, 0, sizeof(At));
  At[2][1] = 0.161;
  At[3][1] = -0.008480655492356989; At[3][2] = 0.335480655492357;
  At[4][1] = 2.8971530571054935;  At[4][2] = -6.359448489975075;  At[4][3] = 4.3622954328695815;
  At[5][1] = 5.325864828439257;   At[5][2] = -11.748883564062828; At[5][3] = 7.4955393428898365;  At[5][4] = -0.09249506636175525;
  At[6][1] = 5.86145544294642;    At[6][2] = -12.92096931784711;  At[6][3] = 8.159367898576159;   At[6][4] = -0.071584973281401; At[6][5] = -0.028269050394068383;
  const double dB[7] = {0, 0.09646076681806523, 0.01, 0.4798896504144996,
                        1.379008574103742, -3.290069515436081, 2.324710524099774};
  double C[7][16]; memset(C, 0, sizeof(C));
  C[1][0] = 1.0;
  for (int s = 2; s <= 6; ++s) {
    C[s][0] = 1.0;
    for (int k = 1; k < 16; ++k) {
      double acc = 0.0;
      for (int l = 1; l < s; ++l) acc += At[s][l]*C[l][k-1];
      C[s][k] = acc;
    }
  }
  double M[16]; memset(M, 0, sizeof(M)); M[0] = 1.0;
  for (int k = 1; k < 16; ++k) {
    double acc = 0.0;
    for (int s = 1; s <= 6; ++s) acc += dB[s]*C[s][k-1];
    M[k] = acc;
  }
  double p64m[16]; p64m[0] = 1.0;
  for (int m = 1; m < 16; ++m) p64m[m] = p64m[m-1]*64.0;

  // harvest scaled coefficient rows of M^n along one pmul chain
  CFX cfx; memset(&cfx, 0, sizeof(cfx));
  CMB cmb; memset(&cmb, 0, sizeof(cmb));
  double cur[16]; memset(cur, 0, sizeof(cur)); cur[0] = 1.0;
  for (int n = 0; n <= 4032; ++n) {
    if (n < 64)  for (int m = 0; m <= 4; ++m) cfx.cf[n][m] = (float)(cur[m]/p64m[m]);
    if ((n & 63) == 0) {
      int j = n >> 6;
      if (j < 64) for (int m = 0; m <= 4; ++m) cfx.cx[j][m] = (float)(cur[m]/p64m[m]);
    }
    if ((n & 255) == 0) {
      int J = n >> 8;
      if (J <= 15) for (int m = 0; m <= 6; ++m) cmb.c[J][m] = (float)(cur[m]/p64m[m]);
    }
    if ((n & 255) == 128) {
      int J = (n - 128) >> 8;
      if (J <= 14) for (int m = 0; m <= 6; ++m) cmb.c[16+J][m] = (float)(cur[m]/p64m[m]);
    }
    pmul16(cur, M, cur);
  }

  // EK: [z^m](M-1)^k / 64^m for the closed-form M^i coefficients
  EK ek; memset(&ek, 0, sizeof(ek));
  {
    double e1[5] = {0,0,0,0,0}, e2[5] = {0,0,0,0,0}, e3[5] = {0,0,0,0,0}, e4[5] = {0,0,0,0,0};
    for (int m = 1; m <= 4; ++m) e1[m] = M[m];
    for (int m = 2; m <= 4; ++m) for (int a = 1; a < m; ++a) e2[m] += e1[a]*e1[m-a];
    for (int m = 3; m <= 4; ++m) for (int a = 2; a < m; ++a) e3[m] += e2[a]*e1[m-a];
    e4[4] = e3[3]*e1[1];
    for (int m = 1; m <= 4; ++m) {
      ek.e[0][m-1] = e1[m]/p64m[m];
      ek.e[1][m-1] = e2[m]/p64m[m];
      ek.e[2][m-1] = e3[m]/p64m[m];
      ek.e[3][m-1] = e4[m]/p64m[m];
    }
  }

  k_vchain<<<293, 256, 0, stream>>>(y0, Bm, ws, out, cmb);
  k_phiT<<<120, 256, 0, stream>>>(ws);
  k_fused<<<1088, 256, 0, stream>>>(ws, out, ek, cfx);
}

// Round 15
// 132.640 us; speedup vs baseline: 1.8276x; 1.0653x over previous
//
#include <hip/hip_runtime.h>
#include <cstring>

#define D 128
#define ROW 16512                 // D + D*D
#define DTF (1.0f/4095.0f)
#define HSTEP (64.0f/4095.0f)     // Zs scale: Zs = (64*dt)*B
#define H4F  (256.0f/4095.0f)     // coarse checkpoint step
#define LDA 132
#define LDB 132
#define NV  5                     // V basis degree-4 (err ~1.5e-4 rel << bf16 floor)

#define XCP_OFF 4096              // x0 vector
#define MAT_OFF 12416

// slot map (each slot = 16384 floats = one 128x128 matrix)
#define S_ZT      3               // Zs transposed
#define S_V(m)    (4+(m))         // V_m = W0*Zs^m, m=0..4 (row-major)
#define S_AT(J)   (11+(J))        // W(256J)^T, J=0..15
#define S_BMT(J)  (27+(J))        // W(256J+128)^T, J=0..14
#define S_PT      42              // PhiT_J row-major, J=0..14

struct __align__(16) F4 { float v[4]; };
typedef float f4v __attribute__((ext_vector_type(4)));

__device__ __forceinline__ float* slotp(float* ws, int k){ return ws + MAT_OFF + (size_t)k*16384; }
__device__ __forceinline__ const float* slotpc(const float* ws, int k){ return ws + MAT_OFF + (size_t)k*16384; }

struct CFX { float cf[64][5]; float cx[64][5]; };  // M^i (deg4), M^(64j) (deg4), /64^m scaled
struct CMB { float c[31][7]; };                    // rows: A_J (J=0..15), BM_J (J=0..14), deg-6
struct EK  { double e[4][4]; };                    // [z^m](M-1)^k / 64^m, k=1..4, m=1..4

// ---------------- 256-thread strip-matmul pieces ----------------
__device__ __forceinline__ void ldA(const float* A, int r0, float (*As)[LDA]) {
  const F4* A4 = (const F4*)(A + (size_t)r0*128);
  for (int q = threadIdx.x; q < 512; q += 256) {
    F4 x = A4[q];
    *(F4*)&As[q>>5][(q&31)<<2] = x;
  }
}
__device__ __forceinline__ void mmcT(const float (*As)[LDA], const float (*Bs)[LDB], F4& o0, F4& o1) {
  const int rl = threadIdx.x >> 5, c0 = (threadIdx.x & 31) << 2;
  F4 a0s, a1s;
  #pragma unroll
  for (int e = 0; e < 4; ++e) { a0s.v[e] = 0.f; a1s.v[e] = 0.f; }
  #pragma unroll 8
  for (int k = 0; k < 128; ++k) {
    const F4 bv = *(const F4*)&Bs[k][c0];
    const float a0 = As[rl][k], a1 = As[rl+8][k];
    #pragma unroll
    for (int e = 0; e < 4; ++e) {
      a0s.v[e] = fmaf(a0, bv.v[e], a0s.v[e]);
      a1s.v[e] = fmaf(a1, bv.v[e], a1s.v[e]);
    }
  }
  o0 = a0s; o1 = a1s;
}

// ---------------- launch 1: V-chain + misc + Horner A^T/BM^T ----------------
__global__ __launch_bounds__(256) void k_vchain(const float* y0, const float* Bm,
                                                float* ws, float* out, CMB cmb) {
  __shared__ float As[16][LDA];
  __shared__ float Bs[128][LDB];
  int b = blockIdx.x, t = threadIdx.x;
  const float* W0 = y0 + D;
  const int rl = t >> 5, c0 = (t & 31) << 2;
  if (b < 32) {
    int m = (b >> 3) + 1, strip = b & 7;
    const F4* B4 = (const F4*)Bm;
    for (int q = t; q < 4096; q += 256) {
      F4 x = B4[q]; F4 o;
      #pragma unroll
      for (int e = 0; e < 4; ++e) o.v[e] = HSTEP * x.v[e];
      *(F4*)&Bs[q>>5][(q&31)<<2] = o;
    }
    ldA(W0, strip*16, As);
    __syncthreads();
    F4 o0, o1;
    for (int p = 0; p < m; ++p) {
      mmcT(As, Bs, o0, o1);
      if (p+1 < m) {
        __syncthreads();
        *(F4*)&As[rl][c0] = o0;
        *(F4*)&As[rl+8][c0] = o1;
        __syncthreads();
      }
    }
    float* Vp = slotp(ws, S_V(m));
    *(F4*)&Vp[(size_t)(strip*16+rl)*128 + c0]   = o0;
    *(F4*)&Vp[(size_t)(strip*16+rl+8)*128 + c0] = o1;
  } else if (b < 36) {
    int base = (b-32)*1024;
    for (int i = 0; i < 4; ++i) {
      int q = base + t + i*256;
      ((F4*)out)[q] = ((const F4*)y0)[q];
    }
  } else if (b == 36) {
    if (t < 128) { out[16384+t] = y0[16384+t]; ws[XCP_OFF+t] = y0[t]; }
  } else if (b < 41) {
    int base = (b-37)*1024;
    F4* Vp = (F4*)slotp(ws, S_V(0));
    for (int i = 0; i < 4; ++i) { int q = base + t + i*256; Vp[q] = ((const F4*)W0)[q]; }
  } else if (b < 45) {
    int base = (b-41)*1024;
    float* ZT = slotp(ws, S_ZT);
    for (int i = 0; i < 4; ++i) {
      int q = base + t + i*256;
      F4 x = ((const F4*)Bm)[q];
      int r = q>>5, cc2 = (q&31)<<2;
      #pragma unroll
      for (int e = 0; e < 4; ++e) ZT[(size_t)(cc2+e)*128 + r] = HSTEP * x.v[e];
    }
  } else {
    int idx = b - 45;
    int mat = idx >> 3, strip = idx & 7;
    int slot = (mat < 16) ? S_AT(mat) : S_BMT(mat-16);
    const float* cc = cmb.c[mat];
    const F4* B4 = (const F4*)Bm;
    for (int q = t; q < 4096; q += 256) {
      F4 x = B4[q]; F4 o;
      #pragma unroll
      for (int e = 0; e < 4; ++e) o.v[e] = HSTEP * x.v[e];
      *(F4*)&Bs[q>>5][(q&31)<<2] = o;
    }
    const F4 s0 = *(const F4*)&W0[(size_t)(strip*16+rl)*128 + c0];
    const F4 s1 = *(const F4*)&W0[(size_t)(strip*16+rl+8)*128 + c0];
    F4 t0, t1;
    #pragma unroll
    for (int e = 0; e < 4; ++e) { t0.v[e] = cc[6]*s0.v[e]; t1.v[e] = cc[6]*s1.v[e]; }
    *(F4*)&As[rl][c0] = t0; *(F4*)&As[rl+8][c0] = t1;
    __syncthreads();
    F4 o0, o1;
    for (int k = 5; k >= 0; --k) {
      mmcT(As, Bs, o0, o1);
      #pragma unroll
      for (int e = 0; e < 4; ++e) { o0.v[e] += cc[k]*s0.v[e]; o1.v[e] += cc[k]*s1.v[e]; }
      if (k > 0) {
        __syncthreads();
        *(F4*)&As[rl][c0] = o0; *(F4*)&As[rl+8][c0] = o1;
        __syncthreads();
      }
    }
    // write transposed: AT[c][r] = A[r][c]
    float* Cp = slotp(ws, slot);
    int r0 = strip*16 + rl;
    #pragma unroll
    for (int e = 0; e < 4; ++e) {
      Cp[(size_t)(c0+e)*128 + r0]     = o0.v[e];
      Cp[(size_t)(c0+e)*128 + r0 + 8] = o1.v[e];
    }
  }
}

// ---------------- launch 2: PhiT_J one-shot (transposed RK4 polynomial) ----------------
__global__ __launch_bounds__(256) void k_phiT(float* ws) {
  __shared__ float Bs1[128][LDB];   // b full
  __shared__ float Bs2[128][LDB];   // ap full
  __shared__ float Aw[16][LDA];     // sa -> u1 -> u2 -> v1
  __shared__ float Asb[16][LDA];    // sb
  int J = blockIdx.x >> 3, strip = blockIdx.x & 7, t = threadIdx.x;
  const int rl = t >> 5, c0 = (t & 31) << 2;
  const float* a  = slotpc(ws, S_AT(J));
  const float* b  = slotpc(ws, S_BMT(J));
  const float* ap = slotpc(ws, S_AT(J+1));
  { const F4* s=(const F4*)b;  for (int q=t;q<4096;q+=256) *(F4*)&Bs1[q>>5][(q&31)<<2]=s[q]; }
  { const F4* s=(const F4*)ap; for (int q=t;q<4096;q+=256) *(F4*)&Bs2[q>>5][(q&31)<<2]=s[q]; }
  ldA(a, strip*16, Aw);
  ldA(b, strip*16, Asb);
  __syncthreads();
  F4 pa0, pa1;
  {
    const F4 p0 = *(const F4*)&ap[(size_t)(strip*16+rl)*128 + c0];
    const F4 p1 = *(const F4*)&ap[(size_t)(strip*16+rl+8)*128 + c0];
    #pragma unroll
    for (int e = 0; e < 4; ++e) {
      pa0.v[e] = Aw[rl][c0+e]   + 4.f*Asb[rl][c0+e]   + p0.v[e];
      pa1.v[e] = Aw[rl+8][c0+e] + 4.f*Asb[rl+8][c0+e] + p1.v[e];
    }
  }
  const float h = H4F, wh = h, wh2 = 0.5f*h*h, wh3 = 0.25f*h*h*h;
  F4 o0, o1;
  // u1 = sa*b
  mmcT(Aw, Bs1, o0, o1);
  #pragma unroll
  for (int e = 0; e < 4; ++e) { pa0.v[e] += wh*o0.v[e]; pa1.v[e] += wh*o1.v[e]; }
  __syncthreads();
  *(F4*)&Aw[rl][c0] = o0; *(F4*)&Aw[rl+8][c0] = o1;
  __syncthreads();
  // u2 = u1*b
  mmcT(Aw, Bs1, o0, o1);
  #pragma unroll
  for (int e = 0; e < 4; ++e) { pa0.v[e] += wh2*o0.v[e]; pa1.v[e] += wh2*o1.v[e]; }
  __syncthreads();
  *(F4*)&Aw[rl][c0] = o0; *(F4*)&Aw[rl+8][c0] = o1;
  __syncthreads();
  // u3 = u2*ap
  mmcT(Aw, Bs2, o0, o1);
  #pragma unroll
  for (int e = 0; e < 4; ++e) { pa0.v[e] += wh3*o0.v[e]; pa1.v[e] += wh3*o1.v[e]; }
  __syncthreads();
  // v1 = sb*b
  mmcT(Asb, Bs1, o0, o1);
  #pragma unroll
  for (int e = 0; e < 4; ++e) { pa0.v[e] += wh*o0.v[e]; pa1.v[e] += wh*o1.v[e]; }
  *(F4*)&Aw[rl][c0] = o0; *(F4*)&Aw[rl+8][c0] = o1;
  __syncthreads();
  // v2 = sb*ap
  mmcT(Asb, Bs2, o0, o1);
  #pragma unroll
  for (int e = 0; e < 4; ++e) { pa0.v[e] += wh*o0.v[e]; pa1.v[e] += wh*o1.v[e]; }
  // v3 = v1*ap
  mmcT(Aw, Bs2, o0, o1);
  #pragma unroll
  for (int e = 0; e < 4; ++e) { pa0.v[e] += wh2*o0.v[e]; pa1.v[e] += wh2*o1.v[e]; }
  float* PT = slotp(ws, S_PT + J);
  const float h6 = h / 6.0f;
  #pragma unroll
  for (int half = 0; half < 2; ++half) {
    int r = strip*16 + rl + half*8;
    F4 pa = half ? pa1 : pa0;
    F4 o;
    #pragma unroll
    for (int e = 0; e < 4; ++e)
      o.v[e] = ((r == c0+e) ? 1.0f : 0.0f) + h6*pa.v[e];
    *(F4*)&PT[(size_t)r*128 + c0] = o;
  }
}

// ---------------- launch 3: fused x-path + LDS-staged contiguous W fill ----------------
// blocks 0..63: (J,w) x-path; blocks 64..1087: fill (g = n-group of 16, qt = quarter)
__global__ __launch_bounds__(256, 2) void k_fused(float* ws, float* out, EK ek, CFX cfx) {
  __shared__ __align__(16) float smf[NV*4096];   // 80 KB
  int t = threadIdx.x;

  if (blockIdx.x >= 64) {
    // ---- W fill: stage V quarters to LDS, write 16 rows x 16 KB contiguous ----
    int bb = blockIdx.x - 64;
    int g = bb >> 2, qt = bb & 3;
    for (int m = 0; m < NV; ++m) {
      const F4* Vq = (const F4*)(slotpc(ws, S_V(m)) + qt*4096);
      F4* L = (F4*)&smf[m*4096];
      for (int q4 = t; q4 < 1024; q4 += 256) L[q4] = Vq[q4];
    }
    __syncthreads();
    for (int nn = 0; nn < 16; ++nn) {
      int n = g*16 + nn, j = n >> 6, i = n & 63;
      float c[5];
      #pragma unroll
      for (int p = 0; p < 5; ++p) {
        float s = 0.f;
        #pragma unroll
        for (int m = 0; m <= 4; ++m) {
          int qm = p - m;
          if (qm >= 0) s = fmaf(cfx.cf[i][m], cfx.cx[j][qm], s);
        }
        c[p] = s;
      }
      float* dst = out + (size_t)n*ROW + D + qt*4096;
      #pragma unroll
      for (int k = 0; k < 4; ++k) {           // quarter = 1024 F4 = 4 x 256 threads
        int qq = k*256 + t;                    // F4 index within quarter [0,1024)
        f4v o = {0.f, 0.f, 0.f, 0.f};
        #pragma unroll
        for (int m = 0; m < NV; ++m) {
          F4 v = *(const F4*)&smf[m*4096 + 4*qq];
          #pragma unroll
          for (int e = 0; e < 4; ++e) o[e] = fmaf(c[m], v.v[e], o[e]);
        }
        *(f4v*)(dst + 4*(size_t)qq) = o;       // PLAIN store: L2 write-combine path
      }
    }
    return;
  }

  // ---- x path: PhiT chain + P/Q-factorized Heun jumps (uses first 3520 floats of smf) ----
  float* za   = smf;            // [5][128]
  float* zb   = smf + 640;      // [5][128]
  float* Pv   = smf + 1280;     // [5][128]
  float* Qv   = smf + 1920;     // [5][128]
  float* xv   = smf + 2560;
  float* kv   = smf + 2688;
  float* red  = smf + 2816;
  float* uv   = smf + 2944;
  float (*cfs)[5] = (float (*)[5])(smf + 3200);  // [64][5]

  int J = blockIdx.x >> 2, w = blockIdx.x & 3;
  int r = t & 127, hh = t >> 7;
  if (t < 128) xv[t] = ws[XCP_OFF + t];
  if (t < 64) { // cfs[il][m] = [Zs^m] M^(w*64+il), closed form via binomials
    double di = (double)(w*64 + t);
    double b1 = di, b2 = b1*(di-1.0)*0.5, b3 = b2*(di-2.0)*(1.0/3.0), b4 = b3*(di-3.0)*0.25;
    cfs[t][0] = 1.f;
    cfs[t][1] = (float)(b1*ek.e[0][0]);
    cfs[t][2] = (float)(b1*ek.e[0][1] + b2*ek.e[1][1]);
    cfs[t][3] = (float)(b1*ek.e[0][2] + b2*ek.e[1][2] + b3*ek.e[2][2]);
    cfs[t][4] = (float)(b1*ek.e[0][3] + b2*ek.e[1][3] + b3*ek.e[2][3] + b4*ek.e[3][3]);
  }
  __syncthreads();

  // serial checkpoint chain via PhiT matrices: xv = x_{256J} (<= 15 matvecs)
  for (int jj = 0; jj < J; ++jj) {
    const float* PT = slotpc(ws, S_PT + jj);
    float s = 0.f;
    #pragma unroll 8
    for (int c = hh*64; c < hh*64+64; ++c) s = fmaf(PT[(size_t)c*128 + r], xv[c], s);
    if (hh) red[r] = s;
    __syncthreads();
    if (!hh) xv[r] = s + red[r];
    __syncthreads();
  }
  if (J > 0 && w == 0 && t < 128) out[(size_t)(256*J)*ROW + t] = xv[t];

  const float* ATJ = slotpc(ws, S_AT(J));
  { // kv = A_J * xv
    float s = 0.f;
    #pragma unroll 8
    for (int c = hh*64; c < hh*64 + 64; ++c) s = fmaf(ATJ[(size_t)c*128 + r], xv[c], s);
    if (hh) red[r] = s;
    __syncthreads();
    if (!hh) kv[r] = s + red[r];
    __syncthreads();
  }
  if (t < 128) { za[t] = xv[t]; zb[t] = kv[t]; }
  __syncthreads();
  const float* ZTg = slotpc(ws, S_ZT);
  for (int m = 1; m <= 4; ++m) {
    float sa = 0.f, sb = 0.f;
    #pragma unroll 8
    for (int c = hh*64; c < hh*64 + 64; ++c) {
      float zv = ZTg[(size_t)c*128 + r];
      sa = fmaf(zv, za[(m-1)*128 + c], sa);
      sb = fmaf(zv, zb[(m-1)*128 + c], sb);
    }
    if (hh) { red[r] = sa; uv[r] = sb; }
    __syncthreads();
    if (!hh) { za[m*128 + r] = sa + red[r]; zb[m*128 + r] = sb + uv[r]; }
    __syncthreads();
  }
  // P[m] = A_J za[m], Q[m] = A_J zb[m]
  for (int m = 0; m <= 4; ++m) {
    float sa = 0.f, sb = 0.f;
    #pragma unroll 8
    for (int c = hh*64; c < hh*64 + 64; ++c) {
      float av = ATJ[(size_t)c*128 + r];
      sa = fmaf(av, za[m*128 + c], sa);
      sb = fmaf(av, zb[m*128 + c], sb);
    }
    if (hh) { red[r] = sa; uv[r] = sb; }
    __syncthreads();
    if (!hh) { Pv[m*128 + r] = sa + red[r]; Qv[m*128 + r] = sb + uv[r]; }
    __syncthreads();
  }
  // out rows: x_{256J+i} = xv + 0.5 h_i (kv + sum_m cfs[i][m](P_m + h_i Q_m))
  float xr = xv[r], kr = kv[r];
  #pragma unroll 4
  for (int l = 0; l < 32; ++l) {
    int il = 2*l + hh;
    int i = w*64 + il;
    if (i >= 1) {
      float hi = i * DTF;
      float k2r = 0.f;
      #pragma unroll
      for (int m = 0; m <= 4; ++m)
        k2r = fmaf(cfs[il][m], Pv[m*128 + r] + hi*Qv[m*128 + r], k2r);
      out[(size_t)(256*J + i)*ROW + r] = xr + 0.5f*hi*(kr + k2r);
    }
  }
}

// ---------------- host ----------------
static void pmul16(const double* a, const double* b, double* o) {
  double r[16];
  for (int i = 0; i < 16; ++i) r[i] = 0.0;
  for (int i = 0; i < 16; ++i) {
    double ai = a[i];
    if (ai == 0.0) continue;
    for (int k = 0; i + k < 16; ++k) r[i+k] += ai*b[k];
  }
  for (int i = 0; i < 16; ++i) o[i] = r[i];
}

extern "C" void kernel_launch(void* const* d_in, const int* in_sizes, int n_in,
                              void* d_out, int out_size, void* d_ws, size_t ws_size,
                              hipStream_t stream) {
  (void)in_sizes; (void)n_in; (void)out_size; (void)ws_size;
  const float* y0 = (const float*)d_in[1];
  const float* Bm = (const float*)d_in[2];
  float* out = (float*)d_out;
  float* ws  = (float*)d_ws;

  // Tsit5 stability polynomial M(z), z = dt*B, via C_s recurrence
  double At[7][7]; memset(At, 0, sizeof(At));
  At[2][1] = 0.161;
  At[3][1] = -0.008480655492356989; At[3][2] = 0.335480655492357;
  At[4][1] = 2.8971530571054935;  At[4][2] = -6.359448489975075;  At[4][3] = 4.3622954328695815;
  At[5][1] = 5.325864828439257;   At[5][2] = -11.748883564062828; At[5][3] = 7.4955393428898365;  At[5][4] = -0.09249506636175525;
  At[6][1] = 5.86145544294642;    At[6][2] = -12.92096931784711;  At[6][3] = 8.159367898576159;   At[6][4] = -0.071584973281401; At[6][5] = -0.028269050394068383;
  const double dB[7] = {0, 0.09646076681806523, 0.01, 0.4798896504144996,
                        1.379008574103742, -3.290069515436081, 2.324710524099774};
  double C[7][16]; memset(C, 0, sizeof(C));
  C[1][0] = 1.0;
  for (int s = 2; s <= 6; ++s) {
    C[s][0] = 1.0;
    for (int k = 1; k < 16; ++k) {
      double acc = 0.0;
      for (int l = 1; l < s; ++l) acc += At[s][l]*C[l][k-1];
      C[s][k] = acc;
    }
  }
  double M[16]; memset(M, 0, sizeof(M)); M[0] = 1.0;
  for (int k = 1; k < 16; ++k) {
    double acc = 0.0;
    for (int s = 1; s <= 6; ++s) acc += dB[s]*C[s][k-1];
    M[k] = acc;
  }
  double p64m[16]; p64m[0] = 1.0;
  for (int m = 1; m < 16; ++m) p64m[m] = p64m[m-1]*64.0;

  // harvest scaled coefficient rows of M^n along one pmul chain
  CFX cfx; memset(&cfx, 0, sizeof(cfx));
  CMB cmb; memset(&cmb, 0, sizeof(cmb));
  double cur[16]; memset(cur, 0, sizeof(cur)); cur[0] = 1.0;
  for (int n = 0; n <= 4032; ++n) {
    if (n < 64)  for (int m = 0; m <= 4; ++m) cfx.cf[n][m] = (float)(cur[m]/p64m[m]);
    if ((n & 63) == 0) {
      int j = n >> 6;
      if (j < 64) for (int m = 0; m <= 4; ++m) cfx.cx[j][m] = (float)(cur[m]/p64m[m]);
    }
    if ((n & 255) == 0) {
      int J = n >> 8;
      if (J <= 15) for (int m = 0; m <= 6; ++m) cmb.c[J][m] = (float)(cur[m]/p64m[m]);
    }
    if ((n & 255) == 128) {
      int J = (n - 128) >> 8;
      if (J <= 14) for (int m = 0; m <= 6; ++m) cmb.c[16+J][m] = (float)(cur[m]/p64m[m]);
    }
    pmul16(cur, M, cur);
  }

  // EK: [z^m](M-1)^k / 64^m for the closed-form M^i coefficients
  EK ek; memset(&ek, 0, sizeof(ek));
  {
    double e1[5] = {0,0,0,0,0}, e2[5] = {0,0,0,0,0}, e3[5] = {0,0,0,0,0}, e4[5] = {0,0,0,0,0};
    for (int m = 1; m <= 4; ++m) e1[m] = M[m];
    for (int m = 2; m <= 4; ++m) for (int a = 1; a < m; ++a) e2[m] += e1[a]*e1[m-a];
    for (int m = 3; m <= 4; ++m) for (int a = 2; a < m; ++a) e3[m] += e2[a]*e1[m-a];
    e4[4] = e3[3]*e1[1];
    for (int m = 1; m <= 4; ++m) {
      ek.e[0][m-1] = e1[m]/p64m[m];
      ek.e[1][m-1] = e2[m]/p64m[m];
      ek.e[2][m-1] = e3[m]/p64m[m];
      ek.e[3][m-1] = e4[m]/p64m[m];
    }
  }

  k_vchain<<<293, 256, 0, stream>>>(y0, Bm, ws, out, cmb);
  k_phiT<<<120, 256, 0, stream>>>(ws);
  k_fused<<<1088, 256, 0, stream>>>(ws, out, ek, cfx);
}